// Round 1
// baseline (2007.346 us; speedup 1.0000x reference)
//
#include <hip/hip_runtime.h>
#include <math.h>

#define T_OUT 96
#define TB (T_OUT + 2)      // 98  beta positions per block
#define NPOS2 (TB + 2)      // 100 x2/t3/x4 positions
#define NPOS1 (TB + 6)      // 104 x1 positions
#define NDIF  (TB + 10)     // 108 dif positions
#define NUU   (TB + 12)     // 110 uu cache
#define NTHREADS 256

__device__ __forceinline__ float elu_f(float x) {
    return x > 0.0f ? x : (__expf(x) - 1.0f);
}
__device__ __forceinline__ float sq_f(float x) { return x * x; }

__global__ __launch_bounds__(NTHREADS) void weno_nn_kernel(
    const float* __restrict__ uu, const float* __restrict__ e_ptr,
    const float* __restrict__ w1, const float* __restrict__ b1,
    const float* __restrict__ w2, const float* __restrict__ b2,
    const float* __restrict__ w3, const float* __restrict__ b3,
    const float* __restrict__ w4, const float* __restrict__ b4,
    const float* __restrict__ w5, const float* __restrict__ b5,
    const float* __restrict__ w6, const float* __restrict__ b6,
    float* __restrict__ out, int n_out, int N)
{
    __shared__ float s_uu[NUU];
    __shared__ float sA[40 * NPOS2];   // dif -> x2 -> x4 -> beta
    __shared__ float sB[80 * NPOS2];   // x1  -> t3 -> x5

    const int tid = threadIdx.x;
    const int J0 = blockIdx.x * T_OUT;
    const int P0 = J0 + 2;             // first beta position
    const int U0 = J0 - 4;             // global index of s_uu[0]

    // ---- stage 0: load uu tile, compute avg-diff ----
    for (int i = tid; i < NUU; i += NTHREADS) {
        int g = U0 + i;
        s_uu[i] = (g >= 0 && g < N) ? uu[g] : 0.0f;
    }
    __syncthreads();
    for (int l = tid; l < NDIF; l += NTHREADS) {
        int g = U0 + 1 + l;            // = P0 - 5 + l
        float v = 0.0f;
        if (g >= 0 && g < N) {
            int j1 = g < N - 2 ? g : N - 2;   // left diff index (clamped)
            int j0 = g - 1 > 0 ? g - 1 : 0;   // right diff index (clamped)
            float dl = s_uu[j1 + 1 - U0] - s_uu[j1 - U0];
            float dr = s_uu[j0 + 1 - U0] - s_uu[j0 - U0];
            v = 0.5f * (dl + dr);
        }
        sA[l] = v;
    }
    __syncthreads();

    // ---- conv1: 1->20 ch, k=5 pad2, elu.  x1 -> sB[oc*NPOS1 + lx] ----
    for (int item = tid; item < 5 * NPOS1; item += NTHREADS) {
        int lx = item % NPOS1;
        int cb = item / NPOS1;         // 0..4, oc = cb*4 + r
        int g = P0 - 3 + lx;
        if (g >= 0 && g < N) {
            float acc[4];
            #pragma unroll
            for (int r = 0; r < 4; ++r) acc[r] = b1[cb * 4 + r];
            #pragma unroll
            for (int k = 0; k < 5; ++k) {
                float xv = sA[lx + k];
                #pragma unroll
                for (int r = 0; r < 4; ++r)
                    acc[r] += w1[(cb * 4 + r) * 5 + k] * xv;
            }
            #pragma unroll
            for (int r = 0; r < 4; ++r)
                sB[(cb * 4 + r) * NPOS1 + lx] = elu_f(acc[r]);
        } else {
            #pragma unroll
            for (int r = 0; r < 4; ++r)
                sB[(cb * 4 + r) * NPOS1 + lx] = 0.0f;
        }
    }
    __syncthreads();

    // ---- conv2: 20->40 ch, k=5 pad2, elu.  x2 -> sA[oc*NPOS2 + lp] ----
    // 250 items: cb(5) x pos-pair(50); 8 oc x 2 pos per thread
    if (tid < 250) {
        int cb = tid / 50;
        int lp = (tid % 50) * 2;
        float acc[8][2];
        #pragma unroll
        for (int r = 0; r < 8; ++r) { acc[r][0] = 0.f; acc[r][1] = 0.f; }
        const float* wbase = w2 + cb * 8 * 100;
        for (int ic = 0; ic < 20; ++ic) {
            float xv[6];
            #pragma unroll
            for (int t = 0; t < 6; ++t) xv[t] = sB[ic * NPOS1 + lp + t];
            const float* wp = wbase + ic * 5;
            #pragma unroll
            for (int r = 0; r < 8; ++r) {
                #pragma unroll
                for (int k = 0; k < 5; ++k) {
                    float w = wp[r * 100 + k];
                    acc[r][0] += w * xv[k];
                    acc[r][1] += w * xv[k + 1];
                }
            }
        }
        int g0 = P0 - 1 + lp;
        #pragma unroll
        for (int r = 0; r < 8; ++r) {
            float bv = b2[cb * 8 + r];
            float v0 = (g0 >= 0 && g0 < N) ? elu_f(acc[r][0] + bv) : 0.0f;
            float v1 = (g0 + 1 >= 0 && g0 + 1 < N) ? elu_f(acc[r][1] + bv) : 0.0f;
            sA[(cb * 8 + r) * NPOS2 + lp] = v0;
            sA[(cb * 8 + r) * NPOS2 + lp + 1] = v1;
        }
    }
    __syncthreads();

    // ---- conv3: 40->80 ch, k=1, elu.  t3 -> sB[oc*NPOS2 + lp] ----
    for (int item = tid; item < 500; item += NTHREADS) {
        int cb = item / 50;            // 0..9
        int lp = (item % 50) * 2;
        float acc[8][2];
        #pragma unroll
        for (int r = 0; r < 8; ++r) { acc[r][0] = 0.f; acc[r][1] = 0.f; }
        const float* wbase = w3 + cb * 8 * 40;
        for (int ic = 0; ic < 40; ++ic) {
            float x0 = sA[ic * NPOS2 + lp];
            float x1v = sA[ic * NPOS2 + lp + 1];
            #pragma unroll
            for (int r = 0; r < 8; ++r) {
                float w = wbase[r * 40 + ic];
                acc[r][0] += w * x0;
                acc[r][1] += w * x1v;
            }
        }
        int g0 = P0 - 1 + lp;
        #pragma unroll
        for (int r = 0; r < 8; ++r) {
            float bv = b3[cb * 8 + r];
            float v0 = (g0 >= 0 && g0 < N) ? elu_f(acc[r][0] + bv) : 0.0f;
            float v1 = (g0 + 1 >= 0 && g0 + 1 < N) ? elu_f(acc[r][1] + bv) : 0.0f;
            sB[(cb * 8 + r) * NPOS2 + lp] = v0;
            sB[(cb * 8 + r) * NPOS2 + lp + 1] = v1;
        }
    }
    __syncthreads();

    // ---- conv4: 80->40 ch, k=1, elu.  x4 -> sA[oc*NPOS2 + lp] ----
    if (tid < 250) {
        int cb = tid / 50;             // 0..4
        int lp = (tid % 50) * 2;
        float acc[8][2];
        #pragma unroll
        for (int r = 0; r < 8; ++r) { acc[r][0] = 0.f; acc[r][1] = 0.f; }
        const float* wbase = w4 + cb * 8 * 80;
        for (int ic = 0; ic < 80; ++ic) {
            float x0 = sB[ic * NPOS2 + lp];
            float x1v = sB[ic * NPOS2 + lp + 1];
            #pragma unroll
            for (int r = 0; r < 8; ++r) {
                float w = wbase[r * 80 + ic];
                acc[r][0] += w * x0;
                acc[r][1] += w * x1v;
            }
        }
        int g0 = P0 - 1 + lp;
        #pragma unroll
        for (int r = 0; r < 8; ++r) {
            float bv = b4[cb * 8 + r];
            float v0 = (g0 >= 0 && g0 < N) ? elu_f(acc[r][0] + bv) : 0.0f;
            float v1 = (g0 + 1 >= 0 && g0 + 1 < N) ? elu_f(acc[r][1] + bv) : 0.0f;
            sA[(cb * 8 + r) * NPOS2 + lp] = v0;
            sA[(cb * 8 + r) * NPOS2 + lp + 1] = v1;
        }
    }
    __syncthreads();

    // ---- conv5: 40->20 ch, k=3 pad1, elu.  x5 -> sB[oc*TB + lp] ----
    // 245 items: cb(5) x pos-pair(49); 4 oc x 2 pos per thread
    if (tid < 245) {
        int cb = tid / 49;             // 0..4, oc = cb*4 + r
        int lp = (tid % 49) * 2;       // 0..96 -> covers 0..97
        float acc[4][2];
        #pragma unroll
        for (int r = 0; r < 4; ++r) { acc[r][0] = 0.f; acc[r][1] = 0.f; }
        const float* wbase = w5 + cb * 4 * 120;
        for (int ic = 0; ic < 40; ++ic) {
            float xv[4];
            #pragma unroll
            for (int t = 0; t < 4; ++t) xv[t] = sA[ic * NPOS2 + lp + t];
            const float* wp = wbase + ic * 3;
            #pragma unroll
            for (int r = 0; r < 4; ++r) {
                #pragma unroll
                for (int k = 0; k < 3; ++k) {
                    float w = wp[r * 120 + k];
                    acc[r][0] += w * xv[k];
                    acc[r][1] += w * xv[k + 1];
                }
            }
        }
        int g0 = P0 + lp;
        #pragma unroll
        for (int r = 0; r < 4; ++r) {
            float bv = b5[cb * 4 + r];
            float v0 = (g0 < N) ? elu_f(acc[r][0] + bv) : 0.0f;
            float v1 = (g0 + 1 < N) ? elu_f(acc[r][1] + bv) : 0.0f;
            sB[(cb * 4 + r) * TB + lp] = v0;
            sB[(cb * 4 + r) * TB + lp + 1] = v1;
        }
    }
    __syncthreads();

    // ---- conv6: 20->1, k=1, sigmoid, +0.1.  beta -> sA[lp] ----
    if (tid < TB) {
        float acc = b6[0];
        #pragma unroll
        for (int c = 0; c < 20; ++c)
            acc += w6[c] * sB[c * TB + tid];
        sA[tid] = 1.0f / (1.0f + __expf(-acc)) + 0.1f;
    }
    __syncthreads();

    // ---- WENO5 ----
    const float eps = e_ptr[0];
    if (tid < T_OUT) {
        int j = J0 + tid;
        if (j < n_out) {
            float a  = s_uu[tid + 5];   // uu[j+1]
            float b  = s_uu[tid + 6];
            float c  = s_uu[tid + 7];
            float d  = s_uu[tid + 8];
            float ee = s_uu[tid + 9];
            float f  = s_uu[tid + 10];  // uu[j+6]
            float m0 = sA[tid];         // beta_mult[j+2]
            float m1 = sA[tid + 1];
            float m2 = sA[tid + 2];

            const float i6 = 1.0f / 6.0f;
            float fp0 = (11.f * d - 7.f * ee + 2.f * f) * i6;
            float fp1 = (2.f * c + 5.f * d - ee) * i6;
            float fp2 = (-b + 5.f * c + 2.f * d) * i6;
            float fn0 = (11.f * c - 7.f * d + 2.f * ee) * i6;
            float fn1 = (2.f * b + 5.f * c - d) * i6;
            float fn2 = (-a + 5.f * b + 2.f * c) * i6;

            const float c1312 = 13.f / 12.f;
            float bp0 = c1312 * sq_f(d - 2.f * ee + f) + 0.25f * sq_f(3.f * d - 4.f * ee + f);
            float bp1 = c1312 * sq_f(c - 2.f * d + ee) + 0.25f * sq_f(c - ee);
            float bp2 = c1312 * sq_f(b - 2.f * c + d) + 0.25f * sq_f(b - 4.f * c + 3.f * d);
            float bn0 = c1312 * sq_f(c - 2.f * d + ee) + 0.25f * sq_f(3.f * c - 4.f * d + ee);
            float bn1 = c1312 * sq_f(b - 2.f * c + d) + 0.25f * sq_f(b - d);
            float bn2 = c1312 * sq_f(a - 2.f * b + c) + 0.25f * sq_f(a - 4.f * b + 3.f * c);

            bp0 *= m0; bp1 *= m1; bp2 *= m2;
            bn0 *= m0; bn1 *= m1; bn2 *= m2;

            float q0 = eps + bp0; q0 *= q0;
            float q1 = eps + bp1; q1 *= q1;
            float q2 = eps + bp2; q2 *= q2;
            float brs = bp2 - bp0; brs *= brs;
            float o0 = 0.1f * (1.f + brs / q0);
            float o1 = 0.6f * (1.f + brs / q1);
            float o2 = 0.3f * (1.f + brs / q2);
            float inv = 1.f / (o0 + o1 + o2);
            float fluxp = (o0 * fp0 + o1 * fp1 + o2 * fp2) * inv;

            q0 = eps + bn0; q0 *= q0;
            q1 = eps + bn1; q1 *= q1;
            q2 = eps + bn2; q2 *= q2;
            brs = bn2 - bn0; brs *= brs;
            o0 = 0.1f * (1.f + brs / q0);
            o1 = 0.6f * (1.f + brs / q1);
            o2 = 0.3f * (1.f + brs / q2);
            inv = 1.f / (o0 + o1 + o2);
            float fluxn = (o0 * fn0 + o1 * fn1 + o2 * fn2) * inv;

            out[j] = fluxp - fluxn;
        }
    }
}

extern "C" void kernel_launch(void* const* d_in, const int* in_sizes, int n_in,
                              void* d_out, int out_size, void* d_ws, size_t ws_size,
                              hipStream_t stream) {
    const float* uu = (const float*)d_in[0];
    const float* e  = (const float*)d_in[1];
    const float* w1 = (const float*)d_in[2];
    const float* b1 = (const float*)d_in[3];
    const float* w2 = (const float*)d_in[4];
    const float* b2 = (const float*)d_in[5];
    const float* w3 = (const float*)d_in[6];
    const float* b3 = (const float*)d_in[7];
    const float* w4 = (const float*)d_in[8];
    const float* b4 = (const float*)d_in[9];
    const float* w5 = (const float*)d_in[10];
    const float* b5 = (const float*)d_in[11];
    const float* w6 = (const float*)d_in[12];
    const float* b6 = (const float*)d_in[13];
    float* out = (float*)d_out;
    const int N = in_sizes[0];
    const int nblocks = (out_size + T_OUT - 1) / T_OUT;
    weno_nn_kernel<<<nblocks, NTHREADS, 0, stream>>>(
        uu, e, w1, b1, w2, b2, w3, b3, w4, b4, w5, b5, w6, b6,
        out, out_size, N);
}

// Round 2
// 1035.215 us; speedup vs baseline: 1.9391x; 1.9391x over previous
//
#include <hip/hip_runtime.h>
#include <math.h>

// Tile geometry: mid layers (x2/t3/x4) hold exactly 128 positions = 64 lanes x 2.
#define TOUT 124            // outputs per block
#define TBETA 126           // beta / x5 positions      (global offset P0)
#define NP 128              // x2 / t3 / x4 positions   (global offset P0-1)
#define NP1 132             // x1 positions             (global offset P0-3)
#define NDIF 136            // dif positions            (global offset P0-5)
#define NUU 138             // uu cache                 (global offset P0-6 = J0-4)
#define NTHREADS 256

__device__ __forceinline__ float elu_f(float x) {
    return x > 0.0f ? x : (__expf(x) - 1.0f);
}
__device__ __forceinline__ float sq_f(float x) { return x * x; }

__global__ __launch_bounds__(NTHREADS) void weno_nn_kernel(
    const float* __restrict__ uu, const float* __restrict__ e_ptr,
    const float* __restrict__ w1, const float* __restrict__ b1,
    const float* __restrict__ w2, const float* __restrict__ b2,
    const float* __restrict__ w3, const float* __restrict__ b3,
    const float* __restrict__ w4, const float* __restrict__ b4,
    const float* __restrict__ w5, const float* __restrict__ b5,
    const float* __restrict__ w6, const float* __restrict__ b6,
    float* __restrict__ out, int n_out, int N)
{
    __shared__ float s_uu[NUU];
    __shared__ float s_dif[NDIF];
    __shared__ float sA[40 * NP];    // x2 -> x4            (20 KB)
    __shared__ float sB[80 * NP];    // x1(20x132) -> t3(80x128) -> x5(20x128)  (40 KB)
    __shared__ float s_beta[NP];

    const int tid  = threadIdx.x;
    const int lane = tid & 63;
    // wave-uniform wave id (forces scalar weight addressing)
    const int Wu   = __builtin_amdgcn_readfirstlane(tid >> 6);
    const int p0   = 2 * lane;                 // this lane's position pair (mid layers)
    const int J0   = blockIdx.x * TOUT;
    const int P0   = J0 + 2;
    const int U0   = J0 - 4;

    // ---- stage 0: uu tile ----
    for (int i = tid; i < NUU; i += NTHREADS) {
        int g = U0 + i;
        s_uu[i] = (g >= 0 && g < N) ? uu[g] : 0.0f;
    }
    __syncthreads();

    // ---- avg-diff ----
    for (int d = tid; d < NDIF; d += NTHREADS) {
        int g = P0 - 5 + d;
        float v = 0.0f;
        if (g >= 0 && g < N) {
            int j1 = g < N - 2 ? g : N - 2;
            int j0 = g - 1 > 0 ? g - 1 : 0;
            float dl = s_uu[j1 + 1 - U0] - s_uu[j1 - U0];
            float dr = s_uu[j0 + 1 - U0] - s_uu[j0 - U0];
            v = 0.5f * (dl + dr);
        }
        s_dif[d] = v;
    }
    __syncthreads();

    // ---- conv1: 1->20, k=5, elu.  x1 -> sB[oc*NP1 + s] ----
    for (int it = tid; it < 20 * 66; it += NTHREADS) {
        int oc = it / 66;
        int s0 = (it % 66) * 2;
        float dv[6];
        #pragma unroll
        for (int t = 0; t < 6; ++t) dv[t] = s_dif[s0 + t];
        float a0 = b1[oc], a1 = b1[oc];
        #pragma unroll
        for (int k = 0; k < 5; ++k) {
            float w = w1[oc * 5 + k];
            a0 += w * dv[k];
            a1 += w * dv[k + 1];
        }
        int g = P0 - 3 + s0;
        sB[oc * NP1 + s0]     = (g >= 0 && g < N)         ? elu_f(a0) : 0.0f;
        sB[oc * NP1 + s0 + 1] = (g + 1 >= 0 && g + 1 < N) ? elu_f(a1) : 0.0f;
    }
    __syncthreads();

    // ---- conv2: 20->40, k=5, elu.  sB(x1) -> sA(x2) ----
    // wave owns 10 oc (2 chunks of 5); lane owns position pair p0,p0+1
    {
        const int gq = P0 - 1 + p0;
        const bool in0 = (gq >= 0 && gq < N), in1 = (gq + 1 >= 0 && gq + 1 < N);
        for (int c = 0; c < 2; ++c) {
            const int oc0 = Wu * 10 + c * 5;
            const float* __restrict__ wr = w2 + oc0 * 100;
            float acc[5][2];
            #pragma unroll
            for (int r = 0; r < 5; ++r) { acc[r][0] = 0.f; acc[r][1] = 0.f; }
            #pragma unroll 4
            for (int ic = 0; ic < 20; ++ic) {
                float xv[6];
                #pragma unroll
                for (int t = 0; t < 6; ++t) xv[t] = sB[ic * NP1 + p0 + t];
                #pragma unroll
                for (int r = 0; r < 5; ++r) {
                    #pragma unroll
                    for (int k = 0; k < 5; ++k) {
                        float w = wr[r * 100 + ic * 5 + k];
                        acc[r][0] += w * xv[k];
                        acc[r][1] += w * xv[k + 1];
                    }
                }
            }
            #pragma unroll
            for (int r = 0; r < 5; ++r) {
                float bv = b2[oc0 + r];
                sA[(oc0 + r) * NP + p0]     = in0 ? elu_f(acc[r][0] + bv) : 0.0f;
                sA[(oc0 + r) * NP + p0 + 1] = in1 ? elu_f(acc[r][1] + bv) : 0.0f;
            }
        }
    }
    __syncthreads();

    // ---- conv3: 40->80, k=1, elu.  sA(x2) -> sB(t3) ----
    {
        const int gq = P0 - 1 + p0;
        const bool in0 = (gq >= 0 && gq < N), in1 = (gq + 1 >= 0 && gq + 1 < N);
        for (int c = 0; c < 4; ++c) {
            const int oc0 = Wu * 20 + c * 5;
            const float* __restrict__ wr = w3 + oc0 * 40;
            float acc[5][2];
            #pragma unroll
            for (int r = 0; r < 5; ++r) { acc[r][0] = 0.f; acc[r][1] = 0.f; }
            #pragma unroll 8
            for (int ic = 0; ic < 40; ++ic) {
                float x0 = sA[ic * NP + p0];
                float x1v = sA[ic * NP + p0 + 1];
                #pragma unroll
                for (int r = 0; r < 5; ++r) {
                    float w = wr[r * 40 + ic];
                    acc[r][0] += w * x0;
                    acc[r][1] += w * x1v;
                }
            }
            #pragma unroll
            for (int r = 0; r < 5; ++r) {
                float bv = b3[oc0 + r];
                sB[(oc0 + r) * NP + p0]     = in0 ? elu_f(acc[r][0] + bv) : 0.0f;
                sB[(oc0 + r) * NP + p0 + 1] = in1 ? elu_f(acc[r][1] + bv) : 0.0f;
            }
        }
    }
    __syncthreads();

    // ---- conv4: 80->40, k=1, elu.  sB(t3) -> sA(x4) ----
    {
        const int gq = P0 - 1 + p0;
        const bool in0 = (gq >= 0 && gq < N), in1 = (gq + 1 >= 0 && gq + 1 < N);
        for (int c = 0; c < 2; ++c) {
            const int oc0 = Wu * 10 + c * 5;
            const float* __restrict__ wr = w4 + oc0 * 80;
            float acc[5][2];
            #pragma unroll
            for (int r = 0; r < 5; ++r) { acc[r][0] = 0.f; acc[r][1] = 0.f; }
            #pragma unroll 8
            for (int ic = 0; ic < 80; ++ic) {
                float x0 = sB[ic * NP + p0];
                float x1v = sB[ic * NP + p0 + 1];
                #pragma unroll
                for (int r = 0; r < 5; ++r) {
                    float w = wr[r * 80 + ic];
                    acc[r][0] += w * x0;
                    acc[r][1] += w * x1v;
                }
            }
            #pragma unroll
            for (int r = 0; r < 5; ++r) {
                float bv = b4[oc0 + r];
                sA[(oc0 + r) * NP + p0]     = in0 ? elu_f(acc[r][0] + bv) : 0.0f;
                sA[(oc0 + r) * NP + p0 + 1] = in1 ? elu_f(acc[r][1] + bv) : 0.0f;
            }
        }
    }
    __syncthreads();

    // ---- conv5: 40->20, k=3, elu.  sA(x4) -> sB(x5, stride NP, 126 used) ----
    if (lane < 63) {                       // 63 pairs cover 126 positions
        const int t0 = p0;                 // x5 local position (global P0 + t0)
        const int oc0 = Wu * 5;
        const float* __restrict__ wr = w5 + oc0 * 120;
        float acc[5][2];
        #pragma unroll
        for (int r = 0; r < 5; ++r) { acc[r][0] = 0.f; acc[r][1] = 0.f; }
        #pragma unroll 8
        for (int ic = 0; ic < 40; ++ic) {
            float xv[4];
            #pragma unroll
            for (int t = 0; t < 4; ++t) xv[t] = sA[ic * NP + t0 + t];
            #pragma unroll
            for (int r = 0; r < 5; ++r) {
                #pragma unroll
                for (int k = 0; k < 3; ++k) {
                    float w = wr[r * 120 + ic * 3 + k];
                    acc[r][0] += w * xv[k];
                    acc[r][1] += w * xv[k + 1];
                }
            }
        }
        const int g = P0 + t0;
        #pragma unroll
        for (int r = 0; r < 5; ++r) {
            float bv = b5[oc0 + r];
            sB[(oc0 + r) * NP + t0]     = (g < N)     ? elu_f(acc[r][0] + bv) : 0.0f;
            sB[(oc0 + r) * NP + t0 + 1] = (g + 1 < N) ? elu_f(acc[r][1] + bv) : 0.0f;
        }
    }
    __syncthreads();

    // ---- conv6: 20->1, k=1, sigmoid + 0.1 ----
    if (tid < TBETA) {
        float acc = b6[0];
        #pragma unroll
        for (int c = 0; c < 20; ++c)
            acc += w6[c] * sB[c * NP + tid];
        s_beta[tid] = 1.0f / (1.0f + __expf(-acc)) + 0.1f;
    }
    __syncthreads();

    // ---- WENO5 ----
    const float eps = e_ptr[0];
    if (tid < TOUT) {
        int j = J0 + tid;
        if (j < n_out) {
            float a  = s_uu[tid + 5];
            float b  = s_uu[tid + 6];
            float c  = s_uu[tid + 7];
            float d  = s_uu[tid + 8];
            float ee = s_uu[tid + 9];
            float f  = s_uu[tid + 10];
            float m0 = s_beta[tid];
            float m1 = s_beta[tid + 1];
            float m2 = s_beta[tid + 2];

            const float i6 = 1.0f / 6.0f;
            float fp0 = (11.f * d - 7.f * ee + 2.f * f) * i6;
            float fp1 = (2.f * c + 5.f * d - ee) * i6;
            float fp2 = (-b + 5.f * c + 2.f * d) * i6;
            float fn0 = (11.f * c - 7.f * d + 2.f * ee) * i6;
            float fn1 = (2.f * b + 5.f * c - d) * i6;
            float fn2 = (-a + 5.f * b + 2.f * c) * i6;

            const float c1312 = 13.f / 12.f;
            float bp0 = c1312 * sq_f(d - 2.f * ee + f) + 0.25f * sq_f(3.f * d - 4.f * ee + f);
            float bp1 = c1312 * sq_f(c - 2.f * d + ee) + 0.25f * sq_f(c - ee);
            float bp2 = c1312 * sq_f(b - 2.f * c + d) + 0.25f * sq_f(b - 4.f * c + 3.f * d);
            float bn0 = c1312 * sq_f(c - 2.f * d + ee) + 0.25f * sq_f(3.f * c - 4.f * d + ee);
            float bn1 = c1312 * sq_f(b - 2.f * c + d) + 0.25f * sq_f(b - d);
            float bn2 = c1312 * sq_f(a - 2.f * b + c) + 0.25f * sq_f(a - 4.f * b + 3.f * c);

            bp0 *= m0; bp1 *= m1; bp2 *= m2;
            bn0 *= m0; bn1 *= m1; bn2 *= m2;

            float q0 = eps + bp0; q0 *= q0;
            float q1 = eps + bp1; q1 *= q1;
            float q2 = eps + bp2; q2 *= q2;
            float brs = bp2 - bp0; brs *= brs;
            float o0 = 0.1f * (1.f + brs / q0);
            float o1 = 0.6f * (1.f + brs / q1);
            float o2 = 0.3f * (1.f + brs / q2);
            float inv = 1.f / (o0 + o1 + o2);
            float fluxp = (o0 * fp0 + o1 * fp1 + o2 * fp2) * inv;

            q0 = eps + bn0; q0 *= q0;
            q1 = eps + bn1; q1 *= q1;
            q2 = eps + bn2; q2 *= q2;
            brs = bn2 - bn0; brs *= brs;
            o0 = 0.1f * (1.f + brs / q0);
            o1 = 0.6f * (1.f + brs / q1);
            o2 = 0.3f * (1.f + brs / q2);
            inv = 1.f / (o0 + o1 + o2);
            float fluxn = (o0 * fn0 + o1 * fn1 + o2 * fn2) * inv;

            out[j] = fluxp - fluxn;
        }
    }
}

extern "C" void kernel_launch(void* const* d_in, const int* in_sizes, int n_in,
                              void* d_out, int out_size, void* d_ws, size_t ws_size,
                              hipStream_t stream) {
    const float* uu = (const float*)d_in[0];
    const float* e  = (const float*)d_in[1];
    const float* w1 = (const float*)d_in[2];
    const float* b1 = (const float*)d_in[3];
    const float* w2 = (const float*)d_in[4];
    const float* b2 = (const float*)d_in[5];
    const float* w3 = (const float*)d_in[6];
    const float* b3 = (const float*)d_in[7];
    const float* w4 = (const float*)d_in[8];
    const float* b4 = (const float*)d_in[9];
    const float* w5 = (const float*)d_in[10];
    const float* b5 = (const float*)d_in[11];
    const float* w6 = (const float*)d_in[12];
    const float* b6 = (const float*)d_in[13];
    float* out = (float*)d_out;
    const int N = in_sizes[0];
    const int nblocks = (out_size + TOUT - 1) / TOUT;
    weno_nn_kernel<<<nblocks, NTHREADS, 0, stream>>>(
        uu, e, w1, b1, w2, b2, w3, b3, w4, b4, w5, b5, w6, b6,
        out, out_size, N);
}